// Round 14
// baseline (111.894 us; speedup 1.0000x reference)
//
#include <hip/hip_runtime.h>
#include <hip/hip_bf16.h>
#include <stdint.h>

// Problem constants (from reference)
#define Bq 32
#define Sq 512
#define Hq 1024
#define Tq 100
#define Fq 512
#define Lq 5
#define EPSq 1e-5f

typedef float fx4 __attribute__((ext_vector_type(4)));
typedef __bf16 bfx8 __attribute__((ext_vector_type(8)));
typedef unsigned short u16x8 __attribute__((ext_vector_type(8)));
typedef unsigned short u16x4 __attribute__((ext_vector_type(4)));

static __device__ __forceinline__ unsigned short f2bf(float f) {
  unsigned int u = __builtin_bit_cast(unsigned int, f);
  return (unsigned short)((u + 0x7fffu + ((u >> 16) & 1u)) >> 16);  // RNE (finite inputs)
}
static __device__ __forceinline__ u16x4 cvt4(float4 x) {
  u16x4 r;
  r[0] = f2bf(x.x); r[1] = f2bf(x.y); r[2] = f2bf(x.z); r[3] = f2bf(x.w);
  return r;
}
// async global->LDS, 16B per lane; LDS dest must be wave-linear (base + lane*16)
static __device__ __forceinline__ void gl_lds16(const void* g, void* l) {
  __builtin_amdgcn_global_load_lds(
      (const __attribute__((address_space(1))) unsigned int*)(uintptr_t)g,
      (__attribute__((address_space(3))) unsigned int*)(uintptr_t)l,
      16, 0, 0);
}

// ---------------------------------------------------------------- W1 [L][H][H] f32 -> W1T [L][e][h] bf16
__global__ void k_prep(const float* __restrict__ w1, unsigned short* __restrict__ w1t) {
  __shared__ float t[32][33];
  int blk = blockIdx.x;
  int l = blk >> 10; int rem = blk & 1023; int tr = rem >> 5; int tc = rem & 31;
  const float* src = w1 + (size_t)l * Hq * Hq;
  unsigned short* dst = w1t + (size_t)l * Hq * Hq;
  int tid = threadIdx.x;
  int tx = tid & 31, ty = tid >> 5;  // 32 x 8
#pragma unroll
  for (int p = 0; p < 4; p++)
    t[ty + 8 * p][tx] = src[(size_t)(tr * 32 + ty + 8 * p) * Hq + tc * 32 + tx];
  __syncthreads();
#pragma unroll
  for (int p = 0; p < 4; p++)
    dst[(size_t)(tc * 32 + ty + 8 * p) * Hq + tr * 32 + tx] = f2bf(t[tx][ty + 8 * p]);
}

// ---------------------------------------------------------------- GEMM1+LN+relu+pool fused
// R14 structural rewrite: block = (batch b, 64-row slice m); tile M=64 x N=1024 (FULL H row)
// -> LN+relu+masked-pool fuse into the epilogue; h1bf (32MB w + 32MB r) and k_ln_pool die.
// tn dimension gone -> each A f32 panel read by EXACTLY ONE block: in-GEMM convert is now
// non-redundant (kills the R9/R11/R13 4x-redundancy failure mode) and the convert pass dies.
// 8 waves 1x8 (wave tile 64x128, 12 ds_read_b128 per 32 MFMA = same 0.375 ratio as the 42us
// config). K: 32 half-steps BK=32; 2-slot LDS dbuf: sB 2x64KB (gl_lds, 8 chunks/thr) +
// sA 2x4KB (A: 1 float4 f32/thr -> cvt4 -> swizzled 8B ds_write; regs ping-pong depth-2).
// vmcnt ledger (queue per iter: [B(j) 8ops, A(j+1) 1op]):
//   top of iter j: wait vmcnt(1) -> drains B(j), KEEPS A(j+1) in flight; +lgkm(0)+barrier
//   (ds-read WAR for slot nxt about to be overwritten + own ds_write visibility).
//   cvt(A(j+1)) at iter-j end: compiler auto-wait vmcnt(9) (B(j+1) 8 + A(j+2) 1 younger) —
//   leaves the B pipeline untouched. Slot nxt DMA/write at iter j is WAR-safe: last read of
//   nxt was iter j-1, retired by this top's lgkm(0)+barrier (R6-proven pattern).
// XCD: all 8 blocks of batch b on one XCD (bid=(b&7)+8*(8*(b>>3)+m)) -> W1[lang] (2MB) L2-hot.
#define HS_ITER(HS, CUR, NXT)                                                        \
  do {                                                                               \
    int cur = (HS) & 1;                                                              \
    if ((HS) < 31)                                                                   \
      asm volatile("s_waitcnt vmcnt(1) lgkmcnt(0)\n\ts_barrier" ::: "memory");       \
    else                                                                             \
      asm volatile("s_waitcnt vmcnt(0) lgkmcnt(0)\n\ts_barrier" ::: "memory");       \
    if ((HS) <= 30) {                                                                \
      int ko = ((HS) + 1) * 32;                                                      \
      int sl = ((HS) + 1) & 1;                                                       \
      _Pragma("unroll") for (int j = 0; j < 8; j++)                                  \
          gl_lds16(gBsrc[j] + ko, (char*)sB[sl] + pB[j]);                            \
    }                                                                                \
    if ((HS) <= 29) {                                                                \
      NXT = *(const float4*)(gAsrc + ((HS) + 2) * 32);                               \
    }                                                                                \
    const char* cA = (const char*)sA[cur];                                           \
    const char* cB = (const char*)sB[cur];                                           \
    bfx8 af[4], bfr[8];                                                              \
    _Pragma("unroll") for (int m = 0; m < 4; m++)                                    \
        af[m] = *(const bfx8*)(cA + aOff[m]);                                        \
    _Pragma("unroll") for (int n = 0; n < 8; n++)                                    \
        bfr[n] = *(const bfx8*)(cB + bOff[n]);                                       \
    __builtin_amdgcn_s_setprio(1);                                                   \
    _Pragma("unroll") for (int m = 0; m < 4; m++)                                    \
      _Pragma("unroll") for (int n = 0; n < 8; n++)                                  \
          acc[m][n] = __builtin_amdgcn_mfma_f32_16x16x32_bf16(af[m], bfr[n],         \
                                                              acc[m][n], 0, 0, 0);  \
    __builtin_amdgcn_s_setprio(0);                                                   \
    if ((HS) <= 30) {                                                                \
      int sl = ((HS) + 1) & 1;                                                       \
      *(u16x4*)((char*)sA[sl] + aW) = cvt4(CUR);                                     \
    }                                                                                \
  } while (0)

__global__ __launch_bounds__(512, 2) void k_gemm1f(const float* __restrict__ seq,
                                                   const unsigned short* __restrict__ w1t,
                                                   const float* __restrict__ b1,
                                                   const float* __restrict__ g1,
                                                   const float* __restrict__ be1,
                                                   const float* __restrict__ mask,
                                                   const int* __restrict__ lid,
                                                   float* __restrict__ partial) {
  __shared__ short sA[2][64 * 32];     // 8 KB  (reused as f32 scratch in epilogue)
  __shared__ short sB[2][1024 * 32];   // 128 KB
  int bid = blockIdx.x;
  int x = bid & 7; int t = bid >> 3; int mblk = t & 7; int b = ((t >> 3) << 3) | x;
  int lang = lid[b];
  const float* Abf = seq + ((size_t)b * Sq + (size_t)mblk * 64) * Hq;  // 64-row f32 panel
  const unsigned short* Bb = w1t + (size_t)lang * Hq * Hq;             // full W1T[lang]

  int tid = threadIdx.x;
  int lane = tid & 63; int w = tid >> 6;  // 8 waves, wave w owns cols [w*128, w*128+128)
  int fr = lane & 15;                     // row/col within 16
  int q = lane >> 4;                      // 16B chunk within 64B row
  int key = ((fr >> 1) & 7) << 4;         // frag-read swizzle key

  // A staging: thread -> 8B bf16 slot c=tid: row R=c>>3, q8=c&7; src = 4 f32
  int R = tid >> 3, q8 = tid & 7;
  int yA = R * 64 + q8 * 8;
  int aW = yA ^ ((yA >> 3) & 0x70);       // key bits from R bits 1-3; 8B slot preserved
  const float* gAsrc = Abf + (size_t)R * Hq + q8 * 4;
  // B staging: 64KB slot = 4096 chunks; thread covers chunks tid + j*512
  const unsigned short* gBsrc[8]; int pB[8];
#pragma unroll
  for (int j = 0; j < 8; j++) {
    int p = (tid + j * 512) * 16;
    int l = p ^ ((p >> 3) & 0x70);
    gBsrc[j] = Bb + (size_t)(l >> 6) * Hq + ((l >> 4) & 3) * 8;
    pB[j] = p;
  }
  // fragment read byte offsets
  int aOff[4], bOff[8];
#pragma unroll
  for (int m = 0; m < 4; m++) aOff[m] = ((m * 16 + fr) * 64 + q * 16) ^ key;
#pragma unroll
  for (int n = 0; n < 8; n++) bOff[n] = ((w * 128 + n * 16 + fr) * 64 + q * 16) ^ key;

  fx4 acc[4][8];
#pragma unroll
  for (int m = 0; m < 4; m++)
#pragma unroll
    for (int n = 0; n < 8; n++) acc[m][n] = (fx4){0.f, 0.f, 0.f, 0.f};

  // prologue: tile0 A inline (load+wait+cvt+write), then B0 DMA (8), then A1 -> rcur.
  // queue entering iter 0: [B0 x8, A1 x1] -> top vmcnt(1) drains B0, keeps A1.
  {
    float4 a0 = *(const float4*)(gAsrc);
    *(u16x4*)((char*)sA[0] + aW) = cvt4(a0);
  }
#pragma unroll
  for (int j = 0; j < 8; j++) gl_lds16(gBsrc[j], (char*)sB[0] + pB[j]);
  float4 rcur, rnxt;
  rcur = *(const float4*)(gAsrc + 32);

  for (int hs = 0; hs < 32; hs += 2) {
    HS_ITER(hs, rcur, rnxt);
    HS_ITER(hs + 1, rnxt, rcur);
  }

  // ---- epilogue: +b1, LN (f32), relu, masked pool -> 1024-float partial ----
  // acc layout: row = m*16 + q*4 + r (in-block), col = w*128 + n*16 + fr.
  __syncthreads();                        // all LDS reads done; reuse sA as f32 scratch
  float* red = (float*)sA;                // [8 waves][64 rows][2] = 4 KB
  float* stats = red + 1024;              // [64 rows][mu,rstd,maskw] = 768 B

  float bv[8], gv[8], bev[8];
#pragma unroll
  for (int n = 0; n < 8; n++) {
    int col = w * 128 + n * 16 + fr;
    bv[n] = b1[lang * Hq + col];
    gv[n] = g1[lang * Hq + col];
    bev[n] = be1[lang * Hq + col];
  }
  // per-lane row partials over its 8 cols, then 16-lane (fr) butterfly
  float rs[4][4], rq[4][4];
#pragma unroll
  for (int m = 0; m < 4; m++)
#pragma unroll
    for (int r = 0; r < 4; r++) {
      float s = 0.f, qq = 0.f;
#pragma unroll
      for (int n = 0; n < 8; n++) {
        float v = acc[m][n][r] + bv[n];
        s += v; qq += v * v;
      }
      rs[m][r] = s; rq[m][r] = qq;
    }
#pragma unroll
  for (int off = 1; off < 16; off <<= 1)
#pragma unroll
    for (int m = 0; m < 4; m++)
#pragma unroll
      for (int r = 0; r < 4; r++) {
        rs[m][r] += __shfl_xor(rs[m][r], off, 64);
        rq[m][r] += __shfl_xor(rq[m][r], off, 64);
      }
  if (fr == 0) {
#pragma unroll
    for (int m = 0; m < 4; m++)
#pragma unroll
      for (int r = 0; r < 4; r++) {
        int row = m * 16 + q * 4 + r;
        red[(w * 64 + row) * 2] = rs[m][r];
        red[(w * 64 + row) * 2 + 1] = rq[m][r];
      }
  }
  __syncthreads();
  if (tid < 64) {
    int row = tid;
    float S = 0.f, Q = 0.f;
#pragma unroll
    for (int w8 = 0; w8 < 8; w8++) {
      S += red[(w8 * 64 + row) * 2];
      Q += red[(w8 * 64 + row) * 2 + 1];
    }
    float mu = S * (1.f / Hq);
    float var = Q * (1.f / Hq) - mu * mu;
    stats[row * 3] = mu;
    stats[row * 3 + 1] = rsqrtf(var + EPSq);
    stats[row * 3 + 2] = mask[b * Sq + mblk * 64 + row];
  }
  __syncthreads();
  float pol[8] = {0.f, 0.f, 0.f, 0.f, 0.f, 0.f, 0.f, 0.f};
#pragma unroll
  for (int m = 0; m < 4; m++)
#pragma unroll
    for (int r = 0; r < 4; r++) {
      int row = m * 16 + q * 4 + r;
      float mu = stats[row * 3], rstd = stats[row * 3 + 1], mw = stats[row * 3 + 2];
#pragma unroll
      for (int n = 0; n < 8; n++) {
        float v = acc[m][n][r] + bv[n];
        float y = (v - mu) * rstd * gv[n] + bev[n];
        pol[n] += mw * fmaxf(y, 0.f);
      }
    }
#pragma unroll
  for (int n = 0; n < 8; n++) {
    pol[n] += __shfl_xor(pol[n], 16, 64);
    pol[n] += __shfl_xor(pol[n], 32, 64);
  }
  if (q == 0) {
#pragma unroll
    for (int n = 0; n < 8; n++)
      partial[((size_t)(b * 8 + mblk)) * Hq + w * 128 + n * 16 + fr] = pol[n];
  }
}

// ---------------------------------------------------------------- fused: reduce partials/masksum + pooled @ W2 split-K
__global__ __launch_bounds__(256) void k_gemm2p(const float* __restrict__ partial,
                                                const float* __restrict__ mask,
                                                const float* __restrict__ w2,
                                                const int* __restrict__ lid,
                                                float* __restrict__ g2part) {
  __shared__ float pl[256];
  __shared__ float wsum[4];
  int blk = blockIdx.x;
  int b = blk >> 3; int ch = (blk >> 2) & 1; int ks = blk & 3;
  int tid = threadIdx.x;
  int lang = lid[b];
  float mv = mask[b * Sq + tid] + mask[b * Sq + 256 + tid];
#pragma unroll
  for (int off = 1; off < 64; off <<= 1) mv += __shfl_xor(mv, off, 64);
  if ((tid & 63) == 0) wsum[tid >> 6] = mv;
  __syncthreads();
  float inv = 1.0f / (wsum[0] + wsum[1] + wsum[2] + wsum[3]);
  float s = 0.f;
#pragma unroll
  for (int c = 0; c < 8; c++) s += partial[((size_t)(b * 8 + c)) * Hq + ks * 256 + tid];
  pl[tid] = s * inv;
  __syncthreads();
  int col = ch * 512 + tid * 2;
  const float* W = w2 + (size_t)lang * Hq * Hq + (size_t)ks * 256 * Hq + col;
  float a0 = 0.f, a1 = 0.f;
  for (int e0 = 0; e0 < 256; e0 += 8) {
    float2 w[8];
#pragma unroll
    for (int j = 0; j < 8; j++) w[j] = *(const float2*)(W + (size_t)(e0 + j) * Hq);
#pragma unroll
    for (int j = 0; j < 8; j++) { float c = pl[e0 + j]; a0 += c * w[j].x; a1 += c * w[j].y; }
  }
  float2* dst = (float2*)(g2part + ((size_t)(b * 4 + ks) * Hq) + col);
  *dst = make_float2(a0, a1);
}

// ---------------------------------------------------------------- fused: sum k-slices + b2 + final matmul split-K
__global__ __launch_bounds__(256) void k_fpart(const float* __restrict__ g2part,
                                               const float* __restrict__ b2,
                                               const int* __restrict__ lid,
                                               const float* __restrict__ lda,
                                               const float* __restrict__ wf,
                                               float* __restrict__ fpart) {
  __shared__ float sc[128];
  int blk = blockIdx.x;
  int b = blk / 9, ks = blk % 9;
  int tid = threadIdx.x;
  int klen = (ks < 8) ? 128 : 100;
  int kbase = (ks < 8) ? ks * 128 : Hq;   // row offset into wf
  if (ks < 8) {
    if (tid < 128) {
      int col = kbase + tid;
      float v = b2[lid[b] * Hq + col];
#pragma unroll
      for (int c = 0; c < 4; c++) v += g2part[((size_t)(b * 4 + c)) * Hq + col];
      sc[tid] = v;
    }
  } else if (tid < 100) {
    sc[tid] = lda[b * Tq + tid];
  }
  __syncthreads();
  const float* W = wf + (size_t)kbase * Fq + tid * 2;
  float a0 = 0.f, a1 = 0.f;
  int k0 = 0;
  for (; k0 + 8 <= klen; k0 += 8) {
    float2 w[8];
#pragma unroll
    for (int j = 0; j < 8; j++) w[j] = *(const float2*)(W + (size_t)(k0 + j) * Fq);
#pragma unroll
    for (int j = 0; j < 8; j++) { float c = sc[k0 + j]; a0 += c * w[j].x; a1 += c * w[j].y; }
  }
  for (; k0 < klen; k0++) {
    float2 w = *(const float2*)(W + (size_t)k0 * Fq);
    float c = sc[k0];
    a0 += c * w.x; a1 += c * w.y;
  }
  float2* dst = (float2*)(fpart + (size_t)blk * Fq + tid * 2);
  *dst = make_float2(a0, a1);
}

// ---------------------------------------------------------------- reduce 9 slices + bf, LN, relu -> f32 out
__global__ __launch_bounds__(512) void k_final2(const float* __restrict__ fpart,
                                                const float* __restrict__ bff,
                                                const float* __restrict__ gf,
                                                const float* __restrict__ betaf,
                                                float* __restrict__ out) {
  __shared__ float rsum[8], rsq[8];
  int b = blockIdx.x; int tid = threadIdx.x;  // 512
  float acc = bff[tid];
#pragma unroll
  for (int ks = 0; ks < 9; ks++) acc += fpart[((size_t)b * 9 + ks) * Fq + tid];
  float s = acc, q = acc * acc;
#pragma unroll
  for (int off = 1; off < 64; off <<= 1) {
    s += __shfl_xor(s, off, 64);
    q += __shfl_xor(q, off, 64);
  }
  int w = tid >> 6, lane = tid & 63;
  if (lane == 0) { rsum[w] = s; rsq[w] = q; }
  __syncthreads();
  float S = 0.f, Q = 0.f;
#pragma unroll
  for (int i = 0; i < 8; i++) { S += rsum[i]; Q += rsq[i]; }
  float mu = S * (1.f / Fq);
  float var = Q * (1.f / Fq) - mu * mu;
  float y = (acc - mu) * rsqrtf(var + EPSq) * gf[tid] + betaf[tid];
  y = fmaxf(y, 0.f);
  out[b * Fq + tid] = y;   // f32 output
}

// ----------------------------------------------------------------
extern "C" void kernel_launch(void* const* d_in, const int* in_sizes, int n_in,
                              void* d_out, int out_size, void* d_ws, size_t ws_size,
                              hipStream_t stream) {
  const float* seq = (const float*)d_in[0];
  const float* mask = (const float*)d_in[1];
  const int* lid = (const int*)d_in[2];
  const float* lda = (const float*)d_in[3];
  const float* W1 = (const float*)d_in[4];
  const float* b1 = (const float*)d_in[5];
  const float* g1 = (const float*)d_in[6];
  const float* be1 = (const float*)d_in[7];
  const float* W2 = (const float*)d_in[8];
  const float* b2 = (const float*)d_in[9];
  const float* Wf = (const float*)d_in[10];
  const float* bff = (const float*)d_in[11];
  const float* gf = (const float*)d_in[12];
  const float* betaf = (const float*)d_in[13];
  float* out = (float*)d_out;

  // workspace layout (~13 MB; h1bf and seqbf both eliminated)
  char* ws = (char*)d_ws;
  unsigned short* w1t = (unsigned short*)(ws);                    // 10,485,760 B
  float* partial = (float*)(ws + 10485760);                       //  1,048,576 B
  float* g2part = (float*)(ws + 11534336);                        //    524,288 B
  float* fpart = (float*)(ws + 12058624);                         //    589,824 B

  k_prep<<<5120, 256, 0, stream>>>(W1, w1t);
  k_gemm1f<<<256, 512, 0, stream>>>(seq, w1t, b1, g1, be1, mask, lid, partial);
  k_gemm2p<<<256, 256, 0, stream>>>(partial, mask, W2, lid, g2part);
  k_fpart<<<288, 256, 0, stream>>>(g2part, b2, lid, lda, Wf, fpart);
  k_final2<<<32, 512, 0, stream>>>(fpart, bff, gf, betaf, out);
}

// Round 15
// 90.973 us; speedup vs baseline: 1.2300x; 1.2300x over previous
//
#include <hip/hip_runtime.h>
#include <hip/hip_bf16.h>
#include <stdint.h>

// Problem constants (from reference)
#define Bq 32
#define Sq 512
#define Hq 1024
#define Tq 100
#define Fq 512
#define Lq 5
#define EPSq 1e-5f

typedef float fx4 __attribute__((ext_vector_type(4)));
typedef __bf16 bfx8 __attribute__((ext_vector_type(8)));
typedef unsigned short u16x8 __attribute__((ext_vector_type(8)));
typedef unsigned short u16x4 __attribute__((ext_vector_type(4)));

static __device__ __forceinline__ unsigned short f2bf(float f) {
  unsigned int u = __builtin_bit_cast(unsigned int, f);
  return (unsigned short)((u + 0x7fffu + ((u >> 16) & 1u)) >> 16);  // RNE (finite inputs)
}
static __device__ __forceinline__ float bf2f(unsigned short s) {
  return __builtin_bit_cast(float, ((unsigned int)s) << 16);
}
static __device__ __forceinline__ u16x8 cvt8(float4 x0, float4 x1) {
  u16x8 r;
  r[0] = f2bf(x0.x); r[1] = f2bf(x0.y); r[2] = f2bf(x0.z); r[3] = f2bf(x0.w);
  r[4] = f2bf(x1.x); r[5] = f2bf(x1.y); r[6] = f2bf(x1.z); r[7] = f2bf(x1.w);
  return r;
}
// async global->LDS, 16B per lane; LDS dest must be wave-linear (base + lane*16)
static __device__ __forceinline__ void gl_lds16(const void* g, void* l) {
  __builtin_amdgcn_global_load_lds(
      (const __attribute__((address_space(1))) unsigned int*)(uintptr_t)g,
      (__attribute__((address_space(3))) unsigned int*)(uintptr_t)l,
      16, 0, 0);
}

// ---------------------------------------------------------------- W1 [L][H][H] f32 -> W1T [L][e][h] bf16
// R15: phase-2 vectorized — lane packs 4 consecutive out-cols (stride-33 LDS reads, ~2-way
// bank alias = free per m136) into ONE u16x4 8B store; 64B contiguous per 8 lanes; single
// pass. (Old version: 4 passes of 2B scalar stores = 128B/wave-store, ~4x under width.)
__global__ void k_prep(const float* __restrict__ w1, unsigned short* __restrict__ w1t) {
  __shared__ float t[32][33];
  int blk = blockIdx.x;
  int l = blk >> 10; int rem = blk & 1023; int tr = rem >> 5; int tc = rem & 31;
  const float* src = w1 + (size_t)l * Hq * Hq;
  unsigned short* dst = w1t + (size_t)l * Hq * Hq;
  int tid = threadIdx.x;
  int tx = tid & 31, ty = tid >> 5;  // 32 x 8 load shape
#pragma unroll
  for (int p = 0; p < 4; p++)
    t[ty + 8 * p][tx] = src[(size_t)(tr * 32 + ty + 8 * p) * Hq + tc * 32 + tx];
  __syncthreads();
  int y0 = tid >> 3, xc = tid & 7;   // out-row y0 (0..31), 4-col chunk xc (0..7)
  u16x4 o;
#pragma unroll
  for (int i = 0; i < 4; i++) o[i] = f2bf(t[4 * xc + i][y0]);
  *(u16x4*)(dst + (size_t)(tc * 32 + y0) * Hq + tr * 32 + 4 * xc) = o;
}

// ---------------------------------------------------------------- GEMM1: H1 = seq @ W1[lang] + b1, bf16 out
// EXACT R13 (best-total pipeline member, 68.5us): in-GEMM A-convert, fence-free cvt-last:
//   iter j: [top vmcnt(8)+lgkm(0)+bar] -> (b) load A(j+3) f32 -> regs [4 ops]
//           (c) DMA B(j+3) [2 ops] -> (d) ds_read frags + setprio MFMA x32
//           (e) LAST: cvt A(j+2) regs (loaded at j-1) + swizzled ds_write -> slot (j+2)&3.
// Ledger: B(t) older than A(t+1) -> drained by iter (t-2)'s (e)-wait. Top vmcnt(8) tight-safe.
// Slot WAR: A-write@j slot (j+2)&3 last read j-2; B-DMA@j slot (j+3)&3 last read j-1.
// (In-GEMM cvt tax vs bf16-input: +26us — three schedules tried, structural; convert-pass
//  alternative measured WORSE in total: 98-99 vs 91.4. This is the best-known config.)
#define HS_ITER(HS, C0A, C0B, C1A, C1B, N0A, N0B, N1A, N1B)                          \
  do {                                                                               \
    int cur = (HS) & 3;                                                              \
    if ((HS) < 30)                                                                   \
      asm volatile("s_waitcnt vmcnt(8) lgkmcnt(0)\n\ts_barrier" ::: "memory");       \
    else                                                                             \
      asm volatile("s_waitcnt vmcnt(0) lgkmcnt(0)\n\ts_barrier" ::: "memory");       \
    if ((HS) <= 28) {                                                                \
      int ko = ((HS) + 3) * 32;                                                      \
      N0A = *(const float4*)(gAf0 + ko); N0B = *(const float4*)(gAf0 + ko + 4);      \
      N1A = *(const float4*)(gAf1 + ko); N1B = *(const float4*)(gAf1 + ko + 4);      \
      int slot = ((HS) + 3) & 3;                                                     \
      gl_lds16(gB[0] + ko, (char*)sB[slot] + dstOff[0]);                             \
      gl_lds16(gB[1] + ko, (char*)sB[slot] + dstOff[1]);                             \
    }                                                                                \
    const char* cA = (const char*)sA[cur];                                           \
    const char* cB = (const char*)sB[cur];                                           \
    bfx8 bfr[4], af[8];                                                              \
    _Pragma("unroll") for (int n = 0; n < 4; n++)                                    \
        bfr[n] = *(const bfx8*)(cB + bOff[n]);                                       \
    _Pragma("unroll") for (int m = 0; m < 8; m++)                                    \
        af[m] = *(const bfx8*)(cA + aOff[m]);                                        \
    __builtin_amdgcn_s_setprio(1);                                                   \
    _Pragma("unroll") for (int m = 0; m < 8; m++)                                    \
      _Pragma("unroll") for (int n = 0; n < 4; n++)                                  \
          acc[m][n] = __builtin_amdgcn_mfma_f32_16x16x32_bf16(af[m], bfr[n],         \
                                                              acc[m][n], 0, 0, 0);  \
    __builtin_amdgcn_s_setprio(0);                                                   \
    if ((HS) <= 29) {                                                                \
      int sa = ((HS) + 2) & 3;                                                       \
      *(u16x8*)((char*)sA[sa] + aW0) = cvt8(C0A, C0B);                               \
      *(u16x8*)((char*)sA[sa] + aW1) = cvt8(C1A, C1B);                               \
    }                                                                                \
  } while (0)

__global__ __launch_bounds__(512, 2) void k_gemm1(const float* __restrict__ seq,
                                                  const unsigned short* __restrict__ w1t,
                                                  const float* __restrict__ b1,
                                                  const int* __restrict__ lid,
                                                  unsigned short* __restrict__ h1bf) {
  __shared__ short sA[4][256 * 32];
  __shared__ short sB[4][256 * 32];
  int bid = blockIdx.x;
  int g = bid & 63; int tn = bid >> 6;   // XCD = bid%8 = g%8: all 4 tn of a (b,tm) co-XCD
  int b = g >> 1; int tm = g & 1;
  int lang = lid[b];
  const float* Abf = seq + (size_t)b * Sq * Hq + (size_t)tm * 256 * Hq;  // f32 A panel
  const unsigned short* Bb = w1t + (size_t)lang * Hq * Hq + (size_t)tn * 256 * Hq;

  int tid = threadIdx.x;
  int lane = tid & 63; int wid = tid >> 6;
  int wr = wid >> 2, wc = wid & 3;       // 2 x 4 wave grid; wave tile 128 x 64
  int fr = lane & 15;                    // A row / B col within 16
  int q = lane >> 4;                     // 16B chunk within 64B row
  int key = ((fr >> 1) & 7) << 4;        // frag-read swizzle key (per-lane const)

  // A: logical chunk c = tid, tid+512 -> row R=c>>2, k-chunk qa=c&3; swizzled write offset
  const float* gAf0; const float* gAf1; int aW0, aW1;
  {
    int c0 = tid;       int R0 = c0 >> 2, q0 = c0 & 3; int y0 = R0 * 64 + q0 * 16;
    int c1 = tid + 512; int R1 = c1 >> 2, q1 = c1 & 3; int y1 = R1 * 64 + q1 * 16;
    aW0 = y0 ^ ((y0 >> 3) & 0x70);       // same involution as frag reads
    aW1 = y1 ^ ((y1 >> 3) & 0x70);
    gAf0 = Abf + (size_t)R0 * Hq + q0 * 8;
    gAf1 = Abf + (size_t)R1 * Hq + q1 * 8;
  }
  // B: gl_lds 16B chunks, linear dest, pre-inverse-swizzled global source (R4+-verified)
  const unsigned short* gB[2]; int dstOff[2];
#pragma unroll
  for (int j = 0; j < 2; j++) {
    int p = (tid + j * 512) * 16;
    int l = p ^ ((p >> 3) & 0x70);
    int R = l >> 6, qa = (l >> 4) & 3;
    gB[j] = Bb + (size_t)R * Hq + qa * 8;
    dstOff[j] = p;
  }

  // fragment read byte offsets (stored)
  int aOff[8], bOff[4];
#pragma unroll
  for (int m = 0; m < 8; m++)
    aOff[m] = ((wr * 128 + m * 16 + fr) * 64 + q * 16) ^ key;
#pragma unroll
  for (int n = 0; n < 4; n++)
    bOff[n] = ((wc * 64 + n * 16 + fr) * 64 + q * 16) ^ key;

  fx4 acc[8][4];
#pragma unroll
  for (int m = 0; m < 8; m++)
#pragma unroll
    for (int n = 0; n < 4; n++) acc[m][n] = (fx4){0.f, 0.f, 0.f, 0.f};

  // prologue: A tiles 0,1 load+cvt+write (inline waits, once). Then queue order
  // [B0, B1, A2->setX, B2] so iter0-top vmcnt(8) drains exactly B0; iter0's (e) drains A2+B1.
  {
    float4 t0a = *(const float4*)(gAf0);      float4 t0b = *(const float4*)(gAf0 + 4);
    float4 t1a = *(const float4*)(gAf1);      float4 t1b = *(const float4*)(gAf1 + 4);
    *(u16x8*)((char*)sA[0] + aW0) = cvt8(t0a, t0b);
    *(u16x8*)((char*)sA[0] + aW1) = cvt8(t1a, t1b);
    t0a = *(const float4*)(gAf0 + 32); t0b = *(const float4*)(gAf0 + 36);
    t1a = *(const float4*)(gAf1 + 32); t1b = *(const float4*)(gAf1 + 36);
    *(u16x8*)((char*)sA[1] + aW0) = cvt8(t0a, t0b);
    *(u16x8*)((char*)sA[1] + aW1) = cvt8(t1a, t1b);
  }
  gl_lds16(gB[0],      (char*)sB[0] + dstOff[0]);
  gl_lds16(gB[1],      (char*)sB[0] + dstOff[1]);
  gl_lds16(gB[0] + 32, (char*)sB[1] + dstOff[0]);
  gl_lds16(gB[1] + 32, (char*)sB[1] + dstOff[1]);
  float4 x0a, x0b, x1a, x1b, y0a, y0b, y1a, y1b;  // setX / setY (named, static — rule #20)
  x0a = *(const float4*)(gAf0 + 64); x0b = *(const float4*)(gAf0 + 68);   // A tile 2 -> setX
  x1a = *(const float4*)(gAf1 + 64); x1b = *(const float4*)(gAf1 + 68);
  gl_lds16(gB[0] + 64, (char*)sB[2] + dstOff[0]);
  gl_lds16(gB[1] + 64, (char*)sB[2] + dstOff[1]);

  // even iter: cvt setX (tile hs+2, loaded at hs-1), load tile hs+3 -> setY; odd: swap.
  for (int hs = 0; hs < 32; hs += 2) {
    HS_ITER(hs,     x0a, x0b, x1a, x1b, y0a, y0b, y1a, y1b);
    HS_ITER(hs + 1, y0a, y0b, y1a, y1b, x0a, x0b, x1a, x1b);
  }

  // epilogue: + b1, convert, store bf16. C/D: row=(lane>>4)*4+r, col=lane&15 (R2-verified)
  unsigned short* Cb = h1bf + (size_t)b * Sq * Hq;
  float bv[4];
#pragma unroll
  for (int n = 0; n < 4; n++)
    bv[n] = b1[lang * Hq + tn * 256 + wc * 64 + n * 16 + fr];
  int r0 = q * 4;
#pragma unroll
  for (int m = 0; m < 8; m++) {
#pragma unroll
    for (int n = 0; n < 4; n++) {
      int col = tn * 256 + wc * 64 + n * 16 + fr;
#pragma unroll
      for (int r = 0; r < 4; r++) {
        int row = tm * 256 + wr * 128 + m * 16 + r0 + r;
        Cb[(size_t)row * Hq + col] = f2bf(acc[m][n][r] + bv[n]);
      }
    }
  }
}

// ---------------------------------------------------------------- LN + relu + masked pool partials
__global__ __launch_bounds__(256) void k_ln_pool(const unsigned short* __restrict__ h1bf,
                                                 const float* __restrict__ g1,
                                                 const float* __restrict__ be1,
                                                 const float* __restrict__ mask,
                                                 const int* __restrict__ lid,
                                                 float* __restrict__ partial) {
  __shared__ float sacc[4][1024];
  int blk = blockIdx.x; int b = blk >> 3; int ch = blk & 7;
  int tid = threadIdx.x; int lane = tid & 63; int w = tid >> 6;
  int lang = lid[b];
  int e0 = lane * 8;
  int e1 = 512 + lane * 8;

  const float4* gp = (const float4*)(g1 + (size_t)lang * Hq);
  const float4* bp = (const float4*)(be1 + (size_t)lang * Hq);
  float4 ga0 = gp[lane * 2], ga1 = gp[lane * 2 + 1];
  float4 gb0 = gp[128 + lane * 2], gb1 = gp[129 + lane * 2];
  float4 ba0 = bp[lane * 2], ba1 = bp[lane * 2 + 1];
  float4 bb0 = bp[128 + lane * 2], bb1 = bp[129 + lane * 2];
  float gA[8] = {ga0.x, ga0.y, ga0.z, ga0.w, ga1.x, ga1.y, ga1.z, ga1.w};
  float gB[8] = {gb0.x, gb0.y, gb0.z, gb0.w, gb1.x, gb1.y, gb1.z, gb1.w};
  float bA[8] = {ba0.x, ba0.y, ba0.z, ba0.w, ba1.x, ba1.y, ba1.z, ba1.w};
  float bB[8] = {bb0.x, bb0.y, bb0.z, bb0.w, bb1.x, bb1.y, bb1.z, bb1.w};

  float acc0[8] = {0, 0, 0, 0, 0, 0, 0, 0}, acc1[8] = {0, 0, 0, 0, 0, 0, 0, 0};

  for (int i = 0; i < 16; i++) {
    int s = ch * 64 + w * 16 + i;
    const unsigned short* rowp = h1bf + ((size_t)b * Sq + s) * Hq;
    u16x8 va = *(const u16x8*)(rowp + e0);
    u16x8 vb = *(const u16x8*)(rowp + e1);
    float xa[8], xb[8];
    float sum = 0.f, sq = 0.f;
#pragma unroll
    for (int j = 0; j < 8; j++) {
      xa[j] = bf2f(va[j]); sum += xa[j]; sq += xa[j] * xa[j];
      xb[j] = bf2f(vb[j]); sum += xb[j]; sq += xb[j] * xb[j];
    }
#pragma unroll
    for (int off = 1; off < 64; off <<= 1) {
      sum += __shfl_xor(sum, off, 64);
      sq += __shfl_xor(sq, off, 64);
    }
    float mu = sum * (1.f / Hq);
    float var = sq * (1.f / Hq) - mu * mu;
    float rstd = rsqrtf(var + EPSq);
    float mw = mask[b * Sq + s];
#pragma unroll
    for (int j = 0; j < 8; j++) {
      float y0 = fmaxf((xa[j] - mu) * rstd * gA[j] + bA[j], 0.f);
      float y1 = fmaxf((xb[j] - mu) * rstd * gB[j] + bB[j], 0.f);
      acc0[j] += mw * y0;
      acc1[j] += mw * y1;
    }
  }
#pragma unroll
  for (int j = 0; j < 8; j++) {
    sacc[w][e0 + j] = acc0[j];
    sacc[w][e1 + j] = acc1[j];
  }
  __syncthreads();
  int e = tid * 4;
#pragma unroll
  for (int j = 0; j < 4; j++)
    partial[(size_t)blk * Hq + e + j] =
        sacc[0][e + j] + sacc[1][e + j] + sacc[2][e + j] + sacc[3][e + j];
}

// ---------------------------------------------------------------- fused: reduce partials/masksum + pooled @ W2 split-K
__global__ __launch_bounds__(256) void k_gemm2p(const float* __restrict__ partial,
                                                const float* __restrict__ mask,
                                                const float* __restrict__ w2,
                                                const int* __restrict__ lid,
                                                float* __restrict__ g2part) {
  __shared__ float pl[256];
  __shared__ float wsum[4];
  int blk = blockIdx.x;
  int b = blk >> 3; int ch = (blk >> 2) & 1; int ks = blk & 3;
  int tid = threadIdx.x;
  int lang = lid[b];
  float mv = mask[b * Sq + tid] + mask[b * Sq + 256 + tid];
#pragma unroll
  for (int off = 1; off < 64; off <<= 1) mv += __shfl_xor(mv, off, 64);
  if ((tid & 63) == 0) wsum[tid >> 6] = mv;
  __syncthreads();
  float inv = 1.0f / (wsum[0] + wsum[1] + wsum[2] + wsum[3]);
  float s = 0.f;
#pragma unroll
  for (int c = 0; c < 8; c++) s += partial[((size_t)(b * 8 + c)) * Hq + ks * 256 + tid];
  pl[tid] = s * inv;
  __syncthreads();
  int col = ch * 512 + tid * 2;
  const float* W = w2 + (size_t)lang * Hq * Hq + (size_t)ks * 256 * Hq + col;
  float a0 = 0.f, a1 = 0.f;
  for (int e0 = 0; e0 < 256; e0 += 8) {
    float2 w[8];
#pragma unroll
    for (int j = 0; j < 8; j++) w[j] = *(const float2*)(W + (size_t)(e0 + j) * Hq);
#pragma unroll
    for (int j = 0; j < 8; j++) { float c = pl[e0 + j]; a0 += c * w[j].x; a1 += c * w[j].y; }
  }
  float2* dst = (float2*)(g2part + ((size_t)(b * 4 + ks) * Hq) + col);
  *dst = make_float2(a0, a1);
}

// ---------------------------------------------------------------- fused: sum k-slices + b2 + final matmul split-K
__global__ __launch_bounds__(256) void k_fpart(const float* __restrict__ g2part,
                                               const float* __restrict__ b2,
                                               const int* __restrict__ lid,
                                               const float* __restrict__ lda,
                                               const float* __restrict__ wf,
                                               float* __restrict__ fpart) {
  __shared__ float sc[128];
  int blk = blockIdx.x;
  int b = blk / 9, ks = blk % 9;
  int tid = threadIdx.x;
  int klen = (ks < 8) ? 128 : 100;
  int kbase = (ks < 8) ? ks * 128 : Hq;   // row offset into wf
  if (ks < 8) {
    if (tid < 128) {
      int col = kbase + tid;
      float v = b2[lid[b] * Hq + col];
#pragma unroll
      for (int c = 0; c < 4; c++) v += g2part[((size_t)(b * 4 + c)) * Hq + col];
      sc[tid] = v;
    }
  } else if (tid < 100) {
    sc[tid] = lda[b * Tq + tid];
  }
  __syncthreads();
  const float* W = wf + (size_t)kbase * Fq + tid * 2;
  float a0 = 0.f, a1 = 0.f;
  int k0 = 0;
  for (; k0 + 8 <= klen; k0 += 8) {
    float2 w[8];
#pragma unroll
    for (int j = 0; j < 8; j++) w[j] = *(const float2*)(W + (size_t)(k0 + j) * Fq);
#pragma unroll
    for (int j = 0; j < 8; j++) { float c = sc[k0 + j]; a0 += c * w[j].x; a1 += c * w[j].y; }
  }
  for (; k0 < klen; k0++) {
    float2 w = *(const float2*)(W + (size_t)k0 * Fq);
    float c = sc[k0];
    a0 += c * w.x; a1 += c * w.y;
  }
  float2* dst = (float2*)(fpart + (size_t)blk * Fq + tid * 2);
  *dst = make_float2(a0, a1);
}

// ---------------------------------------------------------------- reduce 9 slices + bf, LN, relu -> f32 out
__global__ __launch_bounds__(512) void k_final2(const float* __restrict__ fpart,
                                                const float* __restrict__ bff,
                                                const float* __restrict__ gf,
                                                const float* __restrict__ betaf,
                                                float* __restrict__ out) {
  __shared__ float rsum[8], rsq[8];
  int b = blockIdx.x; int tid = threadIdx.x;  // 512
  float acc = bff[tid];
#pragma unroll
  for (int ks = 0; ks < 9; ks++) acc += fpart[((size_t)b * 9 + ks) * Fq + tid];
  float s = acc, q = acc * acc;
#pragma unroll
  for (int off = 1; off < 64; off <<= 1) {
    s += __shfl_xor(s, off, 64);
    q += __shfl_xor(q, off, 64);
  }
  int w = tid >> 6, lane = tid & 63;
  if (lane == 0) { rsum[w] = s; rsq[w] = q; }
  __syncthreads();
  float S = 0.f, Q = 0.f;
#pragma unroll
  for (int i = 0; i < 8; i++) { S += rsum[i]; Q += rsq[i]; }
  float mu = S * (1.f / Fq);
  float var = Q * (1.f / Fq) - mu * mu;
  float y = (acc - mu) * rsqrtf(var + EPSq) * gf[tid] + betaf[tid];
  y = fmaxf(y, 0.f);
  out[b * Fq + tid] = y;   // f32 output
}

// ----------------------------------------------------------------
extern "C" void kernel_launch(void* const* d_in, const int* in_sizes, int n_in,
                              void* d_out, int out_size, void* d_ws, size_t ws_size,
                              hipStream_t stream) {
  const float* seq = (const float*)d_in[0];
  const float* mask = (const float*)d_in[1];
  const int* lid = (const int*)d_in[2];
  const float* lda = (const float*)d_in[3];
  const float* W1 = (const float*)d_in[4];
  const float* b1 = (const float*)d_in[5];
  const float* g1 = (const float*)d_in[6];
  const float* be1 = (const float*)d_in[7];
  const float* W2 = (const float*)d_in[8];
  const float* b2 = (const float*)d_in[9];
  const float* Wf = (const float*)d_in[10];
  const float* bff = (const float*)d_in[11];
  const float* gf = (const float*)d_in[12];
  const float* betaf = (const float*)d_in[13];
  float* out = (float*)d_out;

  // workspace layout (~46 MB; no seqbf)
  char* ws = (char*)d_ws;
  unsigned short* w1t = (unsigned short*)(ws);                    // 10,485,760 B
  unsigned short* h1bf = (unsigned short*)(ws + 10485760);        // 33,554,432 B
  float* partial = (float*)(ws + 44040192);                       //  1,048,576 B
  float* g2part = (float*)(ws + 45088768);                        //    524,288 B
  float* fpart = (float*)(ws + 45613056);                         //    589,824 B

  k_prep<<<5120, 256, 0, stream>>>(W1, w1t);
  k_gemm1<<<256, 512, 0, stream>>>(seq, w1t, b1, lid, h1bf);
  k_ln_pool<<<256, 256, 0, stream>>>(h1bf, g1, be1, mask, lid, partial);
  k_gemm2p<<<256, 256, 0, stream>>>(partial, mask, W2, lid, g2part);
  k_fpart<<<288, 256, 0, stream>>>(g2part, b2, lid, lda, Wf, fpart);
  k_final2<<<32, 512, 0, stream>>>(fpart, bff, gf, betaf, out);
}